// Round 7
// baseline (9392.357 us; speedup 1.0000x reference)
//
#include <hip/hip_runtime.h>
#include <hip/hip_fp16.h>
#include <cstdint>
#include <cstddef>

#define L_SEQ 2046      // subsampled sequence length
#define NBATCH 32
#define HID 256
#define M_PAD 65536     // padded row count (l2*32+n), 65472 real rows

typedef _Float16 h2vec  __attribute__((ext_vector_type(2)));
typedef _Float16 half8v __attribute__((ext_vector_type(8)));
typedef float    f32x4  __attribute__((ext_vector_type(4)));
typedef unsigned short u16x4 __attribute__((ext_vector_type(4)));

static __device__ __forceinline__ uint32_t pack2(float a, float b) {
  __half2 h = __floats2half2_rn(a, b);
  return __builtin_bit_cast(uint32_t, h);
}

static __device__ __forceinline__ float u16f(unsigned short u) {
  return __half2float(__builtin_bit_cast(__half, u));
}

static __device__ __forceinline__ void gload_lds16(const void* g, void* l) {
  __builtin_amdgcn_global_load_lds(
      (const __attribute__((address_space(1))) void*)g,
      (__attribute__((address_space(3))) void*)l, 16, 0, 0);
}

// ---- fused conv1 + im2col(for conv2 at even positions), output f16 ----
__global__ void k_conv_im2col(const float* __restrict__ X,
                              const float* __restrict__ W1,
                              const float* __restrict__ b1,
                              __half* __restrict__ A1h) {
  int j   = threadIdx.x;     // 0..383
  int row = blockIdx.x;      // 0..65535
  int l2 = row >> 5, n = row & 31;
  float v = 0.f;
  if (l2 < L_SEQ) {
    int ci = j / 3;
    int k  = j - 3 * ci;
    int p  = 2 * l2 + k;
    const float* xb = X + (size_t)n * 13 * 4096 + p;
    const float* w  = W1 + ci * 39;
    float acc = b1[ci];
#pragma unroll
    for (int c = 0; c < 13; c++) {
      const float* xp = xb + (size_t)c * 4096;
      acc += xp[0] * w[3*c+0] + xp[1] * w[3*c+1] + xp[2] * w[3*c+2];
    }
    v = acc;
  }
  A1h[(size_t)row * 384 + j] = __float2half(v);
}

// ---- f32 -> f16 elementwise (weight pre-convert) ----
__global__ void k_cvt_h(const float* __restrict__ src, __half* __restrict__ dst,
                        int nelem) {
  int i = blockIdx.x * 256 + threadIdx.x;
  if (i < nelem) dst[i] = __float2half(src[i]);
}

// ---- combined bias: biasD[i] = bih[i] + (i<512 ? bhh[i] : 0)  (r,z folded) ----
__global__ void k_biascomb(const float* __restrict__ bih_f,
                           const float* __restrict__ bhh_f,
                           const float* __restrict__ bih_b,
                           const float* __restrict__ bhh_b,
                           float* __restrict__ outFb, float* __restrict__ outBb) {
  int i = blockIdx.x * 256 + threadIdx.x;
  if (i < 768) {
    float af = i < 512 ? bhh_f[i] : 0.f;
    float ab = i < 512 ? bhh_b[i] : 0.f;
    outFb[i] = bih_f[i] + af;
    outBb[i] = bih_b[i] + ab;
  }
}

// ---- MFMA GEMM: C_f16[M][ldC](+col_off) = A_f16[M][K] @ B_f16[N][K]^T + bias
__global__ __launch_bounds__(256, 3) void k_gemm_mfma(
    const __half* __restrict__ A, const __half* __restrict__ Bh,
    const float* __restrict__ bias, __half* __restrict__ C,
    int K, int ldC, int col_off) {
  __shared__ __half Asl[128 * 64];   // 16 KiB
  __shared__ __half Bsl[128 * 64];   // 16 KiB
  const int tid  = threadIdx.x;
  const int wave = tid >> 6, lane = tid & 63;
  const int m_blk = blockIdx.x * 128;
  const int n_blk = blockIdx.y * 128;
  const int wm = wave >> 1, wn = wave & 1;

  f32x4 acc[4][4];
#pragma unroll
  for (int i = 0; i < 4; i++)
#pragma unroll
    for (int j = 0; j < 4; j++) acc[i][j] = (f32x4)0.f;

  int srow[4], sko[4];
#pragma unroll
  for (int i = 0; i < 4; i++) {
    int s = (i * 4 + wave) * 64 + lane;
    srow[i] = s >> 3;
    sko[i]  = (s & 7) ^ ((s >> 3) & 7);
  }

  for (int kc = 0; kc < K; kc += 64) {
#pragma unroll
    for (int i = 0; i < 4; i++) {
      int s = (i * 4 + wave) * 64 + lane;
      gload_lds16(A + (size_t)(m_blk + srow[i]) * K + kc + sko[i] * 8,
                  &Asl[s * 8]);
    }
#pragma unroll
    for (int i = 0; i < 4; i++) {
      int s = (i * 4 + wave) * 64 + lane;
      gload_lds16(Bh + (size_t)(n_blk + srow[i]) * K + kc + sko[i] * 8,
                  &Bsl[s * 8]);
    }
    __syncthreads();   // compiler drains vmcnt(0) before s_barrier
#pragma unroll
    for (int kb = 0; kb < 2; kb++) {
      half8v af[4], bf[4];
#pragma unroll
      for (int mi = 0; mi < 4; mi++) {
        int row = wm * 64 + mi * 16 + (lane & 15);
        int c   = (kb * 4 + (lane >> 4)) ^ (row & 7);
        af[mi] = *(const half8v*)&Asl[row * 64 + c * 8];
      }
#pragma unroll
      for (int ni = 0; ni < 4; ni++) {
        int row = wn * 64 + ni * 16 + (lane & 15);
        int c   = (kb * 4 + (lane >> 4)) ^ (row & 7);
        bf[ni] = *(const half8v*)&Bsl[row * 64 + c * 8];
      }
#pragma unroll
      for (int mi = 0; mi < 4; mi++)
#pragma unroll
        for (int ni = 0; ni < 4; ni++)
          acc[mi][ni] = __builtin_amdgcn_mfma_f32_16x16x32_f16(
              af[mi], bf[ni], acc[mi][ni], 0, 0, 0);
    }
    __syncthreads();
  }
#pragma unroll
  for (int ni = 0; ni < 4; ni++) {
    int col = wn * 64 + ni * 16 + (lane & 15);
    float bj = bias[n_blk + col];
#pragma unroll
    for (int mi = 0; mi < 4; mi++) {
      int row0 = m_blk + wm * 64 + mi * 16 + (lane >> 4) * 4;
#pragma unroll
      for (int r = 0; r < 4; r++) {
        C[(size_t)(row0 + r) * ldC + col_off + n_blk + col] =
            __float2half(acc[mi][ni][r] + bj);
      }
    }
  }
}

// ---- pack Whh into MFMA A-frags for v12 ----
// Consumer: wave w (0..7), lane l.  Frag index f = t6*8 + ks, t6 = gate*2+j.
// Holds Whh[gate*256 + w*32 + j*16 + (l&15)][ks*32 + (l>>4)*8 .. +8).
// Linear uint4 addr: ((d*8 + w)*48 + f)*64 + l.
__global__ void k_packw4(const float* __restrict__ Whh_f,
                         const float* __restrict__ Whh_b,
                         uint4* __restrict__ Wpk) {
  int idx = blockIdx.x * 256 + threadIdx.x;   // 0..49151
  int d  = idx / 24576;
  int r  = idx - d * 24576;
  int w  = r / 3072;
  int r2 = r - w * 3072;
  int t6 = r2 >> 9;          // 0..5
  int r3 = r2 & 511;
  int ks = r3 >> 6;
  int l  = r3 & 63;
  int gate = t6 >> 1, j = t6 & 1;
  int row = gate * 256 + w * 32 + j * 16 + (l & 15);
  int k0  = ks * 32 + (l >> 4) * 8;
  const float* W = d ? Whh_b : Whh_f;
  const float* src = W + (size_t)row * 256 + k0;
  uint4 o;
  o.x = pack2(src[0], src[1]);
  o.y = pack2(src[2], src[3]);
  o.z = pack2(src[4], src[5]);
  o.w = pack2(src[6], src[7]);
  Wpk[(size_t)idx] = o;
}

// ---- GRU recurrence v12: pure-MFMA, batch-as-N (full 16), 4 blocks ----
// blocks = dir(2) x batch-half(2, 16 batches = full N tile); 512 threads
// (8 waves, 2/SIMD, 256-VGPR budget).  Wave w owns g-rows [w*32,w*32+32):
// 6 M-tiles (r/z/n x j) x 8 K-frags = 48 A-frags register-resident (MFMA
// reads A from VGPR or AGPR natively).  H in LDS as [granule k/8][n] 16B
// granules, double-buffered: B-frag ds_read_b128 spreads 64 lanes over all
// 8 four-bank slots (b128 floor, no conflicts -- v10's layout had 16
// lanes/slot = 4.19M conflict cycles).  Activation fully in-register, all
// 64 lanes x 8 values.  gi in registers, 6x dwordx2/lane, prefetched one
// step ahead (dense row coverage -> no fetch inflation).  One barrier/step.
__global__ __attribute__((amdgpu_flat_work_group_size(512, 512),
                          amdgpu_waves_per_eu(2, 2)))
void k_gru(
    const __half* __restrict__ gih, const uint4* __restrict__ Wpk,
    const float* __restrict__ bhh_f, const float* __restrict__ bhh_b,
    float* __restrict__ outF, __half* __restrict__ outBh,
    float* __restrict__ hT) {
  const int blk = blockIdx.x;       // 0..3
  const int dir = blk >> 1;         // 0 fwd, 1 bwd
  const int nh  = blk & 1;          // batch half
  const int tid = threadIdx.x;
  const int w   = tid >> 6;         // wave 0..7
  const int l   = tid & 63;
  const int n   = l & 15;           // B-column = batch within tile
  const int hi  = l >> 4;           // k-quad within frag / row-quad in C
  const int n_glob = nh * 16 + n;

  // ---- A-frags (register/AGPR resident across the whole loop)
  uint4 wa[48];
  {
    const uint4* wp = Wpk + ((size_t)(dir * 8 + w) * 48) * 64 + l;
#pragma unroll
    for (int f = 0; f < 48; f++) wa[f] = wp[f * 64];
  }

  const float* bhh = dir ? bhh_b : bhh_f;
  f32x4 bhn[2];
  bhn[0] = *(const f32x4*)&bhh[512 + w * 32 + 0 * 16 + hi * 4];
  bhn[1] = *(const f32x4*)&bhh[512 + w * 32 + 1 * 16 + hi * 4];

  // H granule layout: H[buf][gq*16 + n] holds h[8*gq .. 8*gq+8) of batch n.
  __shared__ __align__(16) uint4 H[2][512];   // 16 KiB
  H[0][tid] = uint4{0u, 0u, 0u, 0u};

  // gi: 6 offsets (gate x j), 4 halves each
  int goff[6];
#pragma unroll
  for (int gate = 0; gate < 3; gate++)
#pragma unroll
    for (int j = 0; j < 2; j++)
      goff[gate * 2 + j] = gate * 256 + w * 32 + j * 16 + hi * 4;

  uint2 gcur[6], gnxt[6];
  {
    const int lidx0 = dir ? (L_SEQ - 1) : 0;
    const __half* base = gih + ((size_t)lidx0 * NBATCH + n_glob) * 1536 + dir * 768;
#pragma unroll
    for (int i = 0; i < 6; i++) gcur[i] = *(const uint2*)(base + goff[i]);
  }

  float hp[2][4];
#pragma unroll
  for (int j = 0; j < 2; j++)
#pragma unroll
    for (int vv = 0; vv < 4; vv++) hp[j][vv] = 0.f;

  __syncthreads();

  int cur = 0;
  for (int t = 0; t < L_SEQ; t++) {
    // ---- prefetch gi(t+1) into gnxt (consumed next step; barrier drains vmcnt)
    if (t + 1 < L_SEQ) {
      const int lidxn = dir ? (L_SEQ - 2 - t) : (t + 1);
      const __half* base = gih + ((size_t)lidxn * NBATCH + n_glob) * 1536 + dir * 768;
#pragma unroll
      for (int i = 0; i < 6; i++) gnxt[i] = *(const uint2*)(base + goff[i]);
    }

    // ---- MFMA phase: gh(tile t6) += Whh_frag x h
    f32x4 acc[6];
#pragma unroll
    for (int i = 0; i < 6; i++) acc[i] = (f32x4)0.f;
    {
      const uint4* Hb = H[cur];
#pragma unroll
      for (int ks = 0; ks < 8; ks++) {
        uint4 bq = Hb[(ks * 4 + hi) * 16 + n];
        half8v bf = __builtin_bit_cast(half8v, bq);
#pragma unroll
        for (int t6 = 0; t6 < 6; t6++)
          acc[t6] = __builtin_amdgcn_mfma_f32_16x16x32_f16(
              __builtin_bit_cast(half8v, wa[t6 * 8 + ks]), bf, acc[t6], 0, 0, 0);
      }
    }

    // ---- activation (all 64 lanes, 8 values each); C/D: row=hi*4+vv, col=n
    const int lidx = dir ? (L_SEQ - 1 - t) : t;
#pragma unroll
    for (int j = 0; j < 2; j++) {
      u16x4 vr = __builtin_bit_cast(u16x4, gcur[0 + j]);
      u16x4 vz = __builtin_bit_cast(u16x4, gcur[2 + j]);
      u16x4 vn = __builtin_bit_cast(u16x4, gcur[4 + j]);
      float hnew[4];
#pragma unroll
      for (int vv = 0; vv < 4; vv++) {
        float hr = acc[0 + j][vv];                // r (bias folded in gih)
        float hz = acc[2 + j][vv];                // z
        float hn = acc[4 + j][vv] + bhn[j][vv];   // n + bhh_n
        float ir  = u16f(vr[vv]);
        float iz  = u16f(vz[vv]);
        float inn = u16f(vn[vv]);
        float rv = 1.f / (1.f + __expf(-(ir + hr)));
        float zz = 1.f / (1.f + __expf(-(iz + hz)));
        float e  = __expf(2.f * (inn + rv * hn));
        float nn = 1.f - 2.f / (e + 1.f);         // tanh, safe at +/-inf
        hnew[vv] = (1.f - zz) * nn + zz * hp[j][vv];
        hp[j][vv] = hnew[vv];
      }
      // h(t+1) -> other buffer: granule w*4+j*2+(hi>>1), col n, 8B half (hi&1)
      uint2 pk;
      pk.x = pack2(hnew[0], hnew[1]);
      pk.y = pack2(hnew[2], hnew[3]);
      const int gran = w * 4 + j * 2 + (hi >> 1);
      *(uint2*)((char*)&H[cur ^ 1][gran * 16 + n] + (hi & 1) * 8) = pk;
      // global output
      const size_t oi = ((size_t)lidx * NBATCH + n_glob) * HID + w * 32 + j * 16 + hi * 4;
      if (dir == 0) {
        f32x4 o; o[0] = hnew[0]; o[1] = hnew[1]; o[2] = hnew[2]; o[3] = hnew[3];
        *(f32x4*)&outF[oi] = o;
      } else {
        *(uint2*)&outBh[oi] = pk;
      }
    }
#pragma unroll
    for (int i = 0; i < 6; i++) gcur[i] = gnxt[i];
    __syncthreads();
    cur ^= 1;
  }

  if (dir == 1) {
#pragma unroll
    for (int j = 0; j < 2; j++) {
      f32x4 o; o[0] = hp[j][0]; o[1] = hp[j][1]; o[2] = hp[j][2]; o[3] = hp[j][3];
      *(f32x4*)&hT[(size_t)n_glob * HID + w * 32 + j * 16 + hi * 4] = o;
    }
  }
}

// ---- combine (in place over outF/d_out): relu(0.5*(out_f + out_b[...,::-1]))
__global__ void k_combine(float* __restrict__ outF,
                          const __half* __restrict__ outBh) {
  int idx = blockIdx.x * 256 + threadIdx.x;
  int c = idx & 255;
  float v = 0.5f * (outF[idx] + __half2float(outBh[idx + 255 - 2 * c]));
  outF[idx] = v > 0.f ? v : 0.f;
}

extern "C" void kernel_launch(void* const* d_in, const int* in_sizes, int n_in,
                              void* d_out, int out_size, void* d_ws, size_t ws_size,
                              hipStream_t stream) {
  const float* X     = (const float*)d_in[0];
  const float* W1    = (const float*)d_in[1];
  const float* b1    = (const float*)d_in[2];
  const float* W2    = (const float*)d_in[3];
  const float* b2    = (const float*)d_in[4];
  const float* Wih_f = (const float*)d_in[5];
  const float* Whh_f = (const float*)d_in[6];
  const float* bih_f = (const float*)d_in[7];
  const float* bhh_f = (const float*)d_in[8];
  const float* Wih_b = (const float*)d_in[9];
  const float* Whh_b = (const float*)d_in[10];
  const float* bih_b = (const float*)d_in[11];
  const float* bhh_b = (const float*)d_in[12];

  // Workspace (bytes), max footprint 251,658,240:
  //   gih   : [0, 201326592)           65536 x 1536 halves (written by gemm2/3)
  //   W2h   : [0, 196608)              alias in gih region; live only for gemm1
  //   A1h   : [201326592, 251658240)   65536 x 384 halves; DEAD after gemm1
  //   outBh : [201326592, 234848256)   alias (written by k_gru)
  //   Wpk   : [234848768, 235635200)   MFMA A-frag pack, written AFTER gemm1
  //   WihfH : [235635200, 236028416)   768x256 f16
  //   WihbH : [236028416, 236421632)   768x256 f16
  //   biasF : [236421632, 236424704)   768 f32 (bih_f + folded bhh_f r/z)
  //   biasB : [236424704, 236427776)   768 f32
  char* wsb = (char*)d_ws;
  __half* gih   = (__half*)(wsb);
  __half* W2h   = (__half*)(wsb);
  __half* A1h   = (__half*)(wsb + 201326592);
  __half* outBh = (__half*)(wsb + 201326592);
  uint4*  Wpk   = (uint4*)(wsb + 234848768);
  __half* WihfH = (__half*)(wsb + 235635200);
  __half* WihbH = (__half*)(wsb + 236028416);
  float*  biasF = (float*)(wsb + 236421632);
  float*  biasB = (float*)(wsb + 236424704);

  float*  outF  = (float*)d_out;
  __half* xsubh = (__half*)d_out;                      // scratch in d_out
  float*  hT    = outF + (size_t)L_SEQ * NBATCH * HID;

  k_conv_im2col<<<dim3(M_PAD), 384, 0, stream>>>(X, W1, b1, A1h);
  k_cvt_h<<<dim3(384), 256, 0, stream>>>(W2, W2h, 98304);
  k_gemm_mfma<<<dim3(512, 2), 256, 0, stream>>>(A1h, W2h, b2, xsubh, 384, 256, 0);
  // A1h dead; Wpk/WihH/bias regions free now
  k_cvt_h<<<dim3(768), 256, 0, stream>>>(Wih_f, WihfH, 196608);
  k_cvt_h<<<dim3(768), 256, 0, stream>>>(Wih_b, WihbH, 196608);
  k_packw4<<<dim3(192), 256, 0, stream>>>(Whh_f, Whh_b, Wpk);
  k_biascomb<<<dim3(3), 256, 0, stream>>>(bih_f, bhh_f, bih_b, bhh_b, biasF, biasB);
  k_gemm_mfma<<<dim3(512, 6), 256, 0, stream>>>(xsubh, WihfH, biasF, gih, 256, 1536, 0);
  k_gemm_mfma<<<dim3(512, 6), 256, 0, stream>>>(xsubh, WihbH, biasB, gih, 256, 1536, 768);
  k_gru<<<dim3(4), 512, 0, stream>>>(gih, Wpk, bhh_f, bhh_b, outF, outBh, hT);
  k_combine<<<dim3(65472), 256, 0, stream>>>(outF, outBh);
}

// Round 8
// 3048.408 us; speedup vs baseline: 3.0811x; 3.0811x over previous
//
#include <hip/hip_runtime.h>
#include <hip/hip_fp16.h>
#include <cstdint>
#include <cstddef>

#define L_SEQ 2046      // subsampled sequence length
#define NBATCH 32
#define HID 256
#define M_PAD 65536     // padded row count (l2*32+n), 65472 real rows

typedef _Float16 h2vec  __attribute__((ext_vector_type(2)));
typedef _Float16 half8v __attribute__((ext_vector_type(8)));
typedef float    f32x4  __attribute__((ext_vector_type(4)));

static __device__ __forceinline__ uint32_t pack2(float a, float b) {
  __half2 h = __floats2half2_rn(a, b);
  return __builtin_bit_cast(uint32_t, h);
}

static __device__ __forceinline__ float fdot2u(uint32_t w, uint32_t h, float c) {
#if __has_builtin(__builtin_amdgcn_fdot2)
  return __builtin_amdgcn_fdot2(__builtin_bit_cast(h2vec, w),
                                __builtin_bit_cast(h2vec, h), c, false);
#else
  __half2 a = __builtin_bit_cast(__half2, w);
  __half2 b = __builtin_bit_cast(__half2, h);
  float2 fa = __half22float2(a), fb = __half22float2(b);
  return c + fa.x * fb.x + fa.y * fb.y;
#endif
}

static __device__ __forceinline__ void gload_lds16(const void* g, void* l) {
  __builtin_amdgcn_global_load_lds(
      (const __attribute__((address_space(1))) void*)g,
      (__attribute__((address_space(3))) void*)l, 16, 0, 0);
}

// ---- fused conv1 + im2col(for conv2 at even positions), output f16 ----
__global__ void k_conv_im2col(const float* __restrict__ X,
                              const float* __restrict__ W1,
                              const float* __restrict__ b1,
                              __half* __restrict__ A1h) {
  int j   = threadIdx.x;     // 0..383
  int row = blockIdx.x;      // 0..65535
  int l2 = row >> 5, n = row & 31;
  float v = 0.f;
  if (l2 < L_SEQ) {
    int ci = j / 3;
    int k  = j - 3 * ci;
    int p  = 2 * l2 + k;
    const float* xb = X + (size_t)n * 13 * 4096 + p;
    const float* w  = W1 + ci * 39;
    float acc = b1[ci];
#pragma unroll
    for (int c = 0; c < 13; c++) {
      const float* xp = xb + (size_t)c * 4096;
      acc += xp[0] * w[3*c+0] + xp[1] * w[3*c+1] + xp[2] * w[3*c+2];
    }
    v = acc;
  }
  A1h[(size_t)row * 384 + j] = __float2half(v);
}

// ---- f32 -> f16 elementwise (weight pre-convert) ----
__global__ void k_cvt_h(const float* __restrict__ src, __half* __restrict__ dst,
                        int nelem) {
  int i = blockIdx.x * 256 + threadIdx.x;
  if (i < nelem) dst[i] = __float2half(src[i]);
}

// ---- MFMA GEMM: C_f16[M][ldC](+col_off) = A_f16[M][K] @ B_f16[N][K]^T + bias
// 128x128 tile, BK=64, 4 waves (2x2), each wave 64x64 out via 4x4 frags of
// 16x16x32_f16.  Staging: global_load_lds 16B with pre-swizzled SOURCE
// addresses (rule 21): LDS slot s=row*8+c holds (row, ko=c^(row&7)) so the
// swizzled ds_read_b128 is bank-conflict-light while the LDS dest of
// global_load_lds stays linear.
__global__ __launch_bounds__(256, 3) void k_gemm_mfma(
    const __half* __restrict__ A, const __half* __restrict__ Bh,
    const float* __restrict__ bias, __half* __restrict__ C,
    int K, int ldC, int col_off) {
  __shared__ __half Asl[128 * 64];   // 16 KiB
  __shared__ __half Bsl[128 * 64];   // 16 KiB
  const int tid  = threadIdx.x;
  const int wave = tid >> 6, lane = tid & 63;
  const int m_blk = blockIdx.x * 128;
  const int n_blk = blockIdx.y * 128;
  const int wm = wave >> 1, wn = wave & 1;

  f32x4 acc[4][4];
#pragma unroll
  for (int i = 0; i < 4; i++)
#pragma unroll
    for (int j = 0; j < 4; j++) acc[i][j] = (f32x4)0.f;

  // staging geometry: issue i stages slot s = (i*4+wave)*64 + lane
  int srow[4], sko[4];
#pragma unroll
  for (int i = 0; i < 4; i++) {
    int s = (i * 4 + wave) * 64 + lane;
    srow[i] = s >> 3;
    sko[i]  = (s & 7) ^ ((s >> 3) & 7);
  }

  for (int kc = 0; kc < K; kc += 64) {
#pragma unroll
    for (int i = 0; i < 4; i++) {
      int s = (i * 4 + wave) * 64 + lane;
      gload_lds16(A + (size_t)(m_blk + srow[i]) * K + kc + sko[i] * 8,
                  &Asl[s * 8]);
    }
#pragma unroll
    for (int i = 0; i < 4; i++) {
      int s = (i * 4 + wave) * 64 + lane;
      gload_lds16(Bh + (size_t)(n_blk + srow[i]) * K + kc + sko[i] * 8,
                  &Bsl[s * 8]);
    }
    __syncthreads();   // compiler drains vmcnt(0) before s_barrier
#pragma unroll
    for (int kb = 0; kb < 2; kb++) {
      half8v af[4], bf[4];
#pragma unroll
      for (int mi = 0; mi < 4; mi++) {
        int row = wm * 64 + mi * 16 + (lane & 15);
        int c   = (kb * 4 + (lane >> 4)) ^ (row & 7);
        af[mi] = *(const half8v*)&Asl[row * 64 + c * 8];
      }
#pragma unroll
      for (int ni = 0; ni < 4; ni++) {
        int row = wn * 64 + ni * 16 + (lane & 15);
        int c   = (kb * 4 + (lane >> 4)) ^ (row & 7);
        bf[ni] = *(const half8v*)&Bsl[row * 64 + c * 8];
      }
#pragma unroll
      for (int mi = 0; mi < 4; mi++)
#pragma unroll
        for (int ni = 0; ni < 4; ni++)
          acc[mi][ni] = __builtin_amdgcn_mfma_f32_16x16x32_f16(
              af[mi], bf[ni], acc[mi][ni], 0, 0, 0);
    }
    __syncthreads();
  }
  // epilogue: D[m=(lane>>4)*4+r][n=lane&15] per fragment
#pragma unroll
  for (int ni = 0; ni < 4; ni++) {
    int col = wn * 64 + ni * 16 + (lane & 15);
    float bj = bias[n_blk + col];
#pragma unroll
    for (int mi = 0; mi < 4; mi++) {
      int row0 = m_blk + wm * 64 + mi * 16 + (lane >> 4) * 4;
#pragma unroll
      for (int r = 0; r < 4; r++) {
        C[(size_t)(row0 + r) * ldC + col_off + n_blk + col] =
            __float2half(acc[mi][ni][r] + bj);
      }
    }
  }
}

// ---- pre-pack Whh (both dirs) to f16, laid out in per-thread uint4 stream ----
// Consumer thread tid (wave=tid>>6, lane=tid&63): kh=lane&1, g=wave*32+(lane>>1).
// Its quad jq (0..47): q=jq/3, gt=jq%3 holds packed pairs of
//   Whh[gt*256+g][kh*128 + 8q .. +8).   Address: Wpk[d*24576 + jq*512 + tid].
__global__ void k_packw(const float* __restrict__ Whh_f,
                        const float* __restrict__ Whh_b,
                        uint4* __restrict__ Wpk) {
  int idx = blockIdx.x * 256 + threadIdx.x;   // 0..49151
  int d   = idx / 24576;
  int r   = idx - d * 24576;
  int jq  = r >> 9;          // 0..47
  int tid = r & 511;
  int q   = jq / 3, gt = jq - 3 * q;
  int lane = tid & 63, wave = tid >> 6;
  int kh = lane & 1, g = wave * 32 + (lane >> 1);
  const float* W = d ? Whh_b : Whh_f;
  const float* src = W + (size_t)(gt * 256 + g) * 256 + kh * 128 + 8 * q;
  uint4 o;
  o.x = pack2(src[0], src[1]);
  o.y = pack2(src[2], src[3]);
  o.z = pack2(src[4], src[5]);
  o.w = pack2(src[6], src[7]);
  Wpk[(size_t)idx] = o;
}

// ---- GRU recurrence v6 (measured-best structure: 2575 us) ----
// 64 blocks = (dir,n); 512 threads (8 waves, 2 waves/SIMD -> 256-VGPR budget).
// kh = lane&1 (k-half), g = wave*32 + (lane>>1). 192 pre-packed f16 weight
// words (48 uint4) per thread, laundered register-resident (unified VGPR/AGPR
// file; VALU sources AGPRs natively -- no tax). h double-buffered in LDS with
// granule swizzle (granule q*2+kh) -> per-q wave read is 2 broadcast addresses
// on disjoint banks. One barrier/step; gi prefetch.  64-block latency-hiding
// beat every issue-count-optimal restructure (v7-v12) -- keep.
__global__ __attribute__((amdgpu_flat_work_group_size(512, 512),
                          amdgpu_waves_per_eu(2, 2)))
void k_gru(
    const __half* __restrict__ gih, const uint4* __restrict__ Wpk,
    const float* __restrict__ bhh_f, const float* __restrict__ bhh_b,
    float* __restrict__ outF, __half* __restrict__ outBh,
    float* __restrict__ hT) {
  const int blk = blockIdx.x;
  const int dir = blk >> 5;    // 0 fwd, 1 bwd
  const int n   = blk & 31;
  const int tid = threadIdx.x;
  const int lane = tid & 63;
  const int kh  = lane & 1;                        // k-half
  const int g   = (tid >> 6) * 32 + (lane >> 1);   // 0..255

  const float* bhh = dir ? bhh_b : bhh_f;

  // coalesced load of this thread's 48 weight quads
  uint4 wv[48];
  {
    const uint4* wp = Wpk + (size_t)dir * 24576 + tid;
#pragma unroll
    for (int j = 0; j < 48; j++) wv[j] = wp[j * 512];
#pragma unroll
    for (int j = 0; j < 48; j++) {
      asm volatile("" : "+v"(wv[j].x), "+v"(wv[j].y), "+v"(wv[j].z), "+v"(wv[j].w));
    }
  }
  const float bh0 = bhh[g];
  const float bh1 = bhh[256 + g];
  const float bh2 = bhh[512 + g];

  // Swizzled hidden state, double-buffered. Granule (16B) index q*2+kh holds
  // h[kh*128 + 8q .. +8). 1 KiB total.
  __shared__ __align__(16) __half hs[2][256];
  if (tid < 128) ((uint32_t*)hs)[tid] = 0u;   // zero hs[0]
  float hp = 0.f;

  const __half* gr = gih + ((size_t)(dir ? (size_t)(L_SEQ - 1) * NBATCH : 0) + n) * 1536
                         + dir * 768 + g;
  const ptrdiff_t gstep = dir ? -(ptrdiff_t)(NBATCH * 1536) : (ptrdiff_t)(NBATCH * 1536);
  __half pi0 = __float2half(0.f), pi1 = pi0, pi2 = pi0;
  if (kh == 0) { pi0 = gr[0]; pi1 = gr[256]; pi2 = gr[512]; }
  __syncthreads();

  for (int t = 0; t < L_SEQ; t++) {
    const uint4* hb = (const uint4*)hs[t & 1];
    float a0 = 0.f, a1 = 0.f, a2 = 0.f;
#pragma unroll
    for (int q = 0; q < 16; q++) {
      uint4 hq = hb[q * 2 + kh];
      uint4 u0 = wv[q * 3 + 0];
      uint4 u1 = wv[q * 3 + 1];
      uint4 u2 = wv[q * 3 + 2];
      a0 = fdot2u(u0.x, hq.x, a0);
      a0 = fdot2u(u0.y, hq.y, a0);
      a0 = fdot2u(u0.z, hq.z, a0);
      a0 = fdot2u(u0.w, hq.w, a0);
      a1 = fdot2u(u1.x, hq.x, a1);
      a1 = fdot2u(u1.y, hq.y, a1);
      a1 = fdot2u(u1.z, hq.z, a1);
      a1 = fdot2u(u1.w, hq.w, a1);
      a2 = fdot2u(u2.x, hq.x, a2);
      a2 = fdot2u(u2.y, hq.y, a2);
      a2 = fdot2u(u2.z, hq.z, a2);
      a2 = fdot2u(u2.w, hq.w, a2);
    }
    // pair reduction over k-halves (no barrier)
    a0 += __shfl_xor(a0, 1);
    a1 += __shfl_xor(a1, 1);
    a2 += __shfl_xor(a2, 1);

    if (kh == 0) {
      float hr = a0 + bh0;
      float hz = a1 + bh1;
      float hn = a2 + bh2;
      float ir  = __half2float(pi0);
      float iz  = __half2float(pi1);
      float inn = __half2float(pi2);
      float rr = 1.f / (1.f + __expf(-(ir + hr)));
      float zz = 1.f / (1.f + __expf(-(iz + hz)));
      float e  = __expf(2.f * (inn + rr * hn));
      float nn = 1.f - 2.f / (e + 1.f);      // tanh, safe at +/-inf
      float hnew = (1.f - zz) * nn + zz * hp;
      hp = hnew;
      __half hh = __float2half(hnew);
      // swizzled write position for h[g]: granule ((g&127)>>3)*2 + (g>>7)
      int swi = ((g & 127) >> 3) * 16 + (g >> 7) * 8 + (g & 7);
      hs[(t + 1) & 1][swi] = hh;
      const int l = dir ? (L_SEQ - 1 - t) : t;
      uint32_t oi = ((uint32_t)l * NBATCH + n) * HID + g;
      if (dir == 0) outF[oi] = hnew;
      else          outBh[oi] = hh;
      gr += gstep;
      if (t + 1 < L_SEQ) { pi0 = gr[0]; pi1 = gr[256]; pi2 = gr[512]; }
    }
    __syncthreads();
  }
  if (dir == 1 && kh == 0) hT[n * HID + g] = hp;
}

// ---- combine, vectorized 8-wide: relu(0.5*(out_f + out_b[...,::-1])) ----
// Thread handles 8 consecutive channels c0..c0+7 of one (l,n) row.
// Partner channels 255-c are the contiguous reversed block [248-c0, 256-c0):
// one uint4 load + in-register half-reversal (word reverse + 16-bit rotate).
__global__ void k_combine(float* __restrict__ outF,
                          const __half* __restrict__ outBh) {
  int i = blockIdx.x * 256 + threadIdx.x;       // 0..2,095,103
  size_t base = (size_t)i * 8;
  int c0 = (int)(base & 255);
  size_t row = base >> 8;
  uint4 hb = *(const uint4*)&outBh[row * 256 + (248 - c0)];
  uint32_t w0 = (hb.w >> 16) | (hb.w << 16);    // (h7,h6)
  uint32_t w1 = (hb.z >> 16) | (hb.z << 16);    // (h5,h4)
  uint32_t w2 = (hb.y >> 16) | (hb.y << 16);    // (h3,h2)
  uint32_t w3 = (hb.x >> 16) | (hb.x << 16);    // (h1,h0)
  float2 f0 = __half22float2(__builtin_bit_cast(__half2, w0));
  float2 f1 = __half22float2(__builtin_bit_cast(__half2, w1));
  float2 f2 = __half22float2(__builtin_bit_cast(__half2, w2));
  float2 f3 = __half22float2(__builtin_bit_cast(__half2, w3));
  f32x4 a = *(const f32x4*)&outF[base];
  f32x4 b = *(const f32x4*)&outF[base + 4];
  f32x4 ra, rb;
  ra[0] = 0.5f * (a[0] + f0.x); ra[1] = 0.5f * (a[1] + f0.y);
  ra[2] = 0.5f * (a[2] + f1.x); ra[3] = 0.5f * (a[3] + f1.y);
  rb[0] = 0.5f * (b[0] + f2.x); rb[1] = 0.5f * (b[1] + f2.y);
  rb[2] = 0.5f * (b[2] + f3.x); rb[3] = 0.5f * (b[3] + f3.y);
#pragma unroll
  for (int j = 0; j < 4; j++) {
    ra[j] = ra[j] > 0.f ? ra[j] : 0.f;
    rb[j] = rb[j] > 0.f ? rb[j] : 0.f;
  }
  *(f32x4*)&outF[base]     = ra;
  *(f32x4*)&outF[base + 4] = rb;
}

extern "C" void kernel_launch(void* const* d_in, const int* in_sizes, int n_in,
                              void* d_out, int out_size, void* d_ws, size_t ws_size,
                              hipStream_t stream) {
  const float* X     = (const float*)d_in[0];
  const float* W1    = (const float*)d_in[1];
  const float* b1    = (const float*)d_in[2];
  const float* W2    = (const float*)d_in[3];
  const float* b2    = (const float*)d_in[4];
  const float* Wih_f = (const float*)d_in[5];
  const float* Whh_f = (const float*)d_in[6];
  const float* bih_f = (const float*)d_in[7];
  const float* bhh_f = (const float*)d_in[8];
  const float* Wih_b = (const float*)d_in[9];
  const float* Whh_b = (const float*)d_in[10];
  const float* bih_b = (const float*)d_in[11];
  const float* bhh_b = (const float*)d_in[12];

  // Workspace (bytes), max footprint 251,658,240 (proven to fit):
  //   gih   : [0, 201326592)           65536 x 1536 halves (written by gemm2/3)
  //   W2h   : [0, 196608)              alias in gih region; live only for gemm1
  //   A1h   : [201326592, 251658240)   65536 x 384 halves; DEAD after gemm1
  //   outBh : [201326592, 234848256)   alias (written by k_gru)
  //   Wpk   : [234848768, 235635200)   2 x 24576 uint4, written AFTER gemm1
  //   WihfH : [235635200, 236028416)   768x256 f16, written AFTER gemm1
  //   WihbH : [236028416, 236421632)   768x256 f16, written AFTER gemm1
  char* wsb = (char*)d_ws;
  __half* gih   = (__half*)(wsb);
  __half* W2h   = (__half*)(wsb);
  __half* A1h   = (__half*)(wsb + 201326592);
  __half* outBh = (__half*)(wsb + 201326592);
  uint4*  Wpk   = (uint4*)(wsb + 234848768);
  __half* WihfH = (__half*)(wsb + 235635200);
  __half* WihbH = (__half*)(wsb + 236028416);

  float*  outF  = (float*)d_out;
  __half* xsubh = (__half*)d_out;                      // scratch in d_out
  float*  hT    = outF + (size_t)L_SEQ * NBATCH * HID;

  k_conv_im2col<<<dim3(M_PAD), 384, 0, stream>>>(X, W1, b1, A1h);
  k_cvt_h<<<dim3(384), 256, 0, stream>>>(W2, W2h, 98304);
  k_gemm_mfma<<<dim3(512, 2), 256, 0, stream>>>(A1h, W2h, b2, xsubh, 384, 256, 0);
  // A1h dead; Wpk/WihH regions free now, W2h dead (gih region reused below)
  k_cvt_h<<<dim3(768), 256, 0, stream>>>(Wih_f, WihfH, 196608);
  k_cvt_h<<<dim3(768), 256, 0, stream>>>(Wih_b, WihbH, 196608);
  k_packw<<<dim3(192), 256, 0, stream>>>(Whh_f, Whh_b, Wpk);
  k_gemm_mfma<<<dim3(512, 6), 256, 0, stream>>>(xsubh, WihfH, bih_f, gih, 256, 1536, 0);
  k_gemm_mfma<<<dim3(512, 6), 256, 0, stream>>>(xsubh, WihbH, bih_b, gih, 256, 1536, 768);
  k_gru<<<dim3(64), 512, 0, stream>>>(gih, Wpk, bhh_f, bhh_b, outF, outBh, hT);
  k_combine<<<dim3(2095104 / 256), 256, 0, stream>>>(outF, outBh);
}